// Round 13
// baseline (1245.680 us; speedup 1.0000x reference)
//
#include <hip/hip_runtime.h>
#include <math.h>

#define VOCAB   50000
#define EMBED   256
#define HIDDEN  64
#define G4      256     // 4*HIDDEN
#define BATCH   64
#define TSEQ    2048
#define NUM_OUT 16

typedef _Float16 f16x8 __attribute__((ext_vector_type(8)));
typedef float    f32x4 __attribute__((ext_vector_type(4)));

#define LOG2E  1.4426950408889634f
#define LOG2E2 2.8853900817779268f

__device__ __forceinline__ float fexp2f(float x) { return __builtin_amdgcn_exp2f(x); }
__device__ __forceinline__ float frcpf(float x)  { return __builtin_amdgcn_rcpf(x); }

// xor-1 neighbor exchange as pure-VALU DPP (quad_perm [1,0,3,2] = 0xB1)
__device__ __forceinline__ int dpp_xor1(int v) {
    return __builtin_amdgcn_update_dpp(0, v, 0xB1, 0xF, 0xF, true);
}
// pack (h_self, h_neighbor) -> f16x2 dword; valid in even lanes
__device__ __forceinline__ int pkpair(float h) {
    int hp = dpp_xor1(__float_as_int(h));
    return __builtin_bit_cast(int,
        __builtin_amdgcn_cvt_pkrtz(h, __int_as_float(hp)));
}

#define REP16(M) M(0) M(1) M(2) M(3) M(4) M(5) M(6) M(7) \
                 M(8) M(9) M(10) M(11) M(12) M(13) M(14) M(15)

// W_ih pre-converted to f16 (bits), [gate][k] row-major. 128 KB static.
__device__ __align__(16) short g_Wf16[G4 * EMBED];

__global__ __launch_bounds__(256) void wcvt_kernel(const float* __restrict__ W_ih) {
    int i = (blockIdx.x * 256 + threadIdx.x) * 4;
    float4 v = *(const float4*)&W_ih[i];
    short4 o;
    o.x = __builtin_bit_cast(short, (_Float16)v.x);
    o.y = __builtin_bit_cast(short, (_Float16)v.y);
    o.z = __builtin_bit_cast(short, (_Float16)v.z);
    o.w = __builtin_bit_cast(short, (_Float16)v.w);
    *(short4*)&g_Wf16[i] = o;
}

// ---------------------------------------------------------------------------
// proj via MFMA f16 (R12 structure). STORE LAYOUT CHANGED for the scan:
// proj2[tok][c*16 + t] where g = t*16 + c  ->  scan lane c reads its 16 gx
// values as 4 coalesced float4.  Value = (dot+bias) * s_gate (log2e / 2log2e).
// ---------------------------------------------------------------------------
__global__ __launch_bounds__(256) void proj_mfma(
    const float* __restrict__ emb,
    const float* __restrict__ b_ih, const float* __restrict__ b_hh,
    float* __restrict__ proj)
{
    __shared__ __align__(16) short As[64][264];   // f16 emb tile, +8 pad

    const int tid  = threadIdx.x;
    const int w    = tid >> 6;
    const int lane = tid & 63;
    const int R0   = blockIdx.x * 64;

    #pragma unroll
    for (int it = 0; it < 16; ++it) {
        int flat = it * 256 + tid;
        int r  = flat >> 6;
        int c4 = flat & 63;
        int row = R0 + r; row = row < VOCAB ? row : VOCAB - 1;
        float4 v = *(const float4*)&emb[(size_t)row * EMBED + c4 * 4];
        short4 o;
        o.x = __builtin_bit_cast(short, (_Float16)v.x);
        o.y = __builtin_bit_cast(short, (_Float16)v.y);
        o.z = __builtin_bit_cast(short, (_Float16)v.z);
        o.w = __builtin_bit_cast(short, (_Float16)v.w);
        *(short4*)&As[r][c4 * 4] = o;
    }
    __syncthreads();

    f32x4 acc[16];
    #pragma unroll
    for (int t = 0; t < 16; ++t) acc[t] = f32x4{0.f, 0.f, 0.f, 0.f};

    const short* arow = &As[w * 16 + (lane & 15)][(lane >> 4) * 8];
    const int boff = (lane & 15) * EMBED + (lane >> 4) * 8;

    #pragma unroll
    for (int kc = 0; kc < 8; ++kc) {
        f16x8 af = *(const f16x8*)(arow + kc * 32);
        #pragma unroll
        for (int t = 0; t < 16; ++t) {
            f16x8 bf = *(const f16x8*)&g_Wf16[t * 16 * EMBED + kc * 32 + boff];
            acc[t] = __builtin_amdgcn_mfma_f32_16x16x32_f16(af, bf, acc[t], 0, 0, 0);
        }
    }

    const int crow0 = R0 + w * 16 + (lane >> 4) * 4;
    const int colin = lane & 15;

    // per-tile (bias, scale): g = t*16 + colin
    float bs[16], sc[16];
    #pragma unroll
    for (int t = 0; t < 16; ++t) {
        int g = t * 16 + colin;
        bs[t] = b_ih[g] + b_hh[g];
        sc[t] = ((t >> 2) == 2) ? LOG2E2 : LOG2E;
    }

    #pragma unroll
    for (int j = 0; j < 4; ++j) {
        int row = crow0 + j;
        if (row < VOCAB) {
            #pragma unroll
            for (int a = 0; a < 4; ++a) {
                float4 o;
                o.x = (acc[4 * a + 0][j] + bs[4 * a + 0]) * sc[4 * a + 0];
                o.y = (acc[4 * a + 1][j] + bs[4 * a + 1]) * sc[4 * a + 1];
                o.z = (acc[4 * a + 2][j] + bs[4 * a + 2]) * sc[4 * a + 2];
                o.w = (acc[4 * a + 3][j] + bs[4 * a + 3]) * sc[4 * a + 3];
                *(float4*)&proj[(size_t)row * G4 + colin * 16 + 4 * a] = o;
            }
        }
    }
}

// ---------------------------------------------------------------------------
// SINGLE-WAVE LSTM scan via MFMA — no barrier, no cross-wave exchange.
// One wave per batch element. gates[256] = h[1x64] @ W_hh^T via 16 N-tiles
// of mfma_f32_16x16x32_f16 x 2 K-chunks; all A-rows replicated = h, so every
// lane holds gates for its col c = lane&15. B-frags (pre-scaled W_hh, f16)
// live in 32 named f16x8 (AGPR-friendly: MFMA reads AGPR natively -> the
// R2-R7 dot2 register phantom cannot occur). h redistribution is intra-wave:
// 4x(dpp+cvt_pk) -> 4 ds_write_b32 -> 2 ds_read_b128, in-order DS pipe.
// ---------------------------------------------------------------------------
__global__ __launch_bounds__(64, 1) void lstm_scan(
    const int* __restrict__ x, const float* __restrict__ proj,
    const float* __restrict__ W_hh,
    const float* __restrict__ bn_gamma, const float* __restrict__ bn_beta,
    const float* __restrict__ bn_mean, const float* __restrict__ bn_var,
    const float* __restrict__ fc_w, const float* __restrict__ fc_b,
    float* __restrict__ out)
{
    const int b    = blockIdx.x;
    const int lane = threadIdx.x;
    const int g    = lane >> 4;     // k-group 0..3
    const int c    = lane & 15;     // unit-mod-16 / output col

    __shared__ int   toks[TSEQ + 4];
    __shared__ __align__(16) int hx[32];   // packed f16 h: dword = s*8 + pair
    __shared__ float hb_s[HIDDEN];

    for (int i = lane; i < TSEQ + 4; i += 64)
        toks[i] = x[b * TSEQ + (i < TSEQ ? i : TSEQ - 1)];
    if (lane < 32) hx[lane] = 0;    // h(-1) = 0

    // B-fragments: tile t covers gates n = 16t+c; k-chunks 0/1.
    // B[t][k] = W_hh[n][k] * s_gate, f16.  32 named f16x8 (128 regs).
#define BDECL(t) f16x8 Ba##t, Bb##t;
    REP16(BDECL)
#undef BDECL
#define BLOAD(t) { \
        const float* wr = W_hh + (size_t)(t * 16 + c) * HIDDEN + g * 8; \
        const float sck = ((t >> 2) == 2) ? LOG2E2 : LOG2E; \
        float4 lo = *(const float4*)wr; \
        float4 hi = *(const float4*)(wr + 4); \
        Ba##t = f16x8{(_Float16)(lo.x*sck), (_Float16)(lo.y*sck), \
                      (_Float16)(lo.z*sck), (_Float16)(lo.w*sck), \
                      (_Float16)(hi.x*sck), (_Float16)(hi.y*sck), \
                      (_Float16)(hi.z*sck), (_Float16)(hi.w*sck)}; \
        lo = *(const float4*)(wr + 32); \
        hi = *(const float4*)(wr + 36); \
        Bb##t = f16x8{(_Float16)(lo.x*sck), (_Float16)(lo.y*sck), \
                      (_Float16)(lo.z*sck), (_Float16)(lo.w*sck), \
                      (_Float16)(hi.x*sck), (_Float16)(hi.y*sck), \
                      (_Float16)(hi.z*sck), (_Float16)(hi.w*sck)}; }
    REP16(BLOAD)
#undef BLOAD

    // persistent state: scaled cells c' = 2*log2e*c, and h per unit-slot s
    float cc0 = 0.f, cc1 = 0.f, cc2 = 0.f, cc3 = 0.f;
    float hs0 = 0.f, hs1 = 0.f, hs2 = 0.f, hs3 = 0.f;

    const float* projc = proj + c * 16;   // lane's gx column base

    // prologue: gx(0), gx(1) in flight (4 float4 each)
    const float4* gp0 = (const float4*)(projc + (size_t)toks[0] * G4);
    const float4* gp1 = (const float4*)(projc + (size_t)toks[1] * G4);
    float4 P0 = gp0[0], P1 = gp0[1], P2 = gp0[2], P3 = gp0[3];
    float4 R0 = gp1[0], R1 = gp1[1], R2 = gp1[2], R3 = gp1[3];

#define STEP(Q0, Q1, Q2, Q3, TT) { \
    const int4* hx4 = (const int4*)hx; \
    int4 a0i = hx4[g]; \
    int4 a1i = hx4[4 + g]; \
    f16x8 A0 = __builtin_bit_cast(f16x8, a0i); \
    f16x8 A1 = __builtin_bit_cast(f16x8, a1i); \
    int tk = toks[(TT) + 2]; \
    const float4* gp = (const float4*)(projc + (size_t)tk * G4); \
    float4 n0 = gp[0], n1 = gp[1], n2 = gp[2], n3 = gp[3]; \
    float gxv[16]; \
    gxv[0]=Q0.x; gxv[1]=Q0.y; gxv[2]=Q0.z; gxv[3]=Q0.w; \
    gxv[4]=Q1.x; gxv[5]=Q1.y; gxv[6]=Q1.z; gxv[7]=Q1.w; \
    gxv[8]=Q2.x; gxv[9]=Q2.y; gxv[10]=Q2.z; gxv[11]=Q2.w; \
    gxv[12]=Q3.x; gxv[13]=Q3.y; gxv[14]=Q3.z; gxv[15]=Q3.w; \
    const f32x4 zz = {0.f, 0.f, 0.f, 0.f}; \
    MFMAS(A0, A1, zz) \
    ACTS() \
    UPD(0, r0, r4, r8,  r12) \
    UPD(1, r1, r5, r9,  r13) \
    UPD(2, r2, r6, r10, r14) \
    UPD(3, r3, r7, r11, r15) \
    int pk0 = pkpair(hs0), pk1 = pkpair(hs1); \
    int pk2 = pkpair(hs2), pk3 = pkpair(hs3); \
    if ((lane & 0x31) == 0) { \
        int bi = c >> 1; \
        hx[bi] = pk0; hx[8 + bi] = pk1; \
        hx[16 + bi] = pk2; hx[24 + bi] = pk3; \
    } \
    Q0 = n0; Q1 = n1; Q2 = n2; Q3 = n3; \
}
#define MFMA1(t, A0, A1, ZZ) \
    f32x4 ac##t = __builtin_amdgcn_mfma_f32_16x16x32_f16(A0, Ba##t, ZZ, 0, 0, 0); \
    ac##t = __builtin_amdgcn_mfma_f32_16x16x32_f16(A1, Bb##t, ac##t, 0, 0, 0);
#define MFMAS(A0, A1, ZZ) \
    MFMA1(0,A0,A1,ZZ)  MFMA1(1,A0,A1,ZZ)  MFMA1(2,A0,A1,ZZ)  MFMA1(3,A0,A1,ZZ) \
    MFMA1(4,A0,A1,ZZ)  MFMA1(5,A0,A1,ZZ)  MFMA1(6,A0,A1,ZZ)  MFMA1(7,A0,A1,ZZ) \
    MFMA1(8,A0,A1,ZZ)  MFMA1(9,A0,A1,ZZ)  MFMA1(10,A0,A1,ZZ) MFMA1(11,A0,A1,ZZ) \
    MFMA1(12,A0,A1,ZZ) MFMA1(13,A0,A1,ZZ) MFMA1(14,A0,A1,ZZ) MFMA1(15,A0,A1,ZZ)
#define ACT1(t) float r##t; { \
    float gv = ac##t[0] + gxv[t]; \
    float e  = fexp2f(gv); \
    float rv = frcpf(e + 1.0f); \
    r##t = ((t) >> 2) == 2 ? fmaf(-2.0f * LOG2E2, rv, LOG2E2) \
                           : fmaf(-1.0f, rv, 1.0f); }
#define ACTS() \
    ACT1(0)  ACT1(1)  ACT1(2)  ACT1(3)  ACT1(4)  ACT1(5)  ACT1(6)  ACT1(7) \
    ACT1(8)  ACT1(9)  ACT1(10) ACT1(11) ACT1(12) ACT1(13) ACT1(14) ACT1(15)
#define UPD(s, RI, RF, RG, RO) { \
    cc##s = fmaf(RF, cc##s, RI * RG); \
    float e2 = fexp2f(cc##s); \
    float rv2 = frcpf(e2 + 1.0f); \
    hs##s = fmaf(-(RO + RO), rv2, RO); }

    for (int t = 0; t < TSEQ; t += 2) {
        STEP(P0, P1, P2, P3, t)
        STEP(R0, R1, R2, R3, t + 1)
    }
#undef STEP
#undef MFMAS
#undef MFMA1
#undef ACTS
#undef ACT1
#undef UPD

    // epilogue: BN on final h (lanes 0-15 hold units 16s+c), then FC
    if ((lane & 48) == 0) {
        float hv[4] = {hs0, hs1, hs2, hs3};
        #pragma unroll
        for (int s = 0; s < 4; ++s) {
            int u = 16 * s + c;
            float hb = (hv[s] - bn_mean[u]) * rsqrtf(bn_var[u] + 1e-5f)
                       * bn_gamma[u] + bn_beta[u];
            hb_s[u] = hb;
        }
    }
    if (lane < NUM_OUT) {
        float s0 = fc_b[lane], s1 = 0.f, s2 = 0.f, s3 = 0.f;
        #pragma unroll
        for (int k = 0; k < HIDDEN; k += 4) {
            s0 = fmaf(hb_s[k + 0], fc_w[lane * HIDDEN + k + 0], s0);
            s1 = fmaf(hb_s[k + 1], fc_w[lane * HIDDEN + k + 1], s1);
            s2 = fmaf(hb_s[k + 2], fc_w[lane * HIDDEN + k + 2], s2);
            s3 = fmaf(hb_s[k + 3], fc_w[lane * HIDDEN + k + 3], s3);
        }
        out[b * NUM_OUT + lane] = (s0 + s1) + (s2 + s3);
    }
}

// ---------------------------------------------------------------------------
extern "C" void kernel_launch(void* const* d_in, const int* in_sizes, int n_in,
                              void* d_out, int out_size, void* d_ws, size_t ws_size,
                              hipStream_t stream) {
    const int*   x        = (const int*)d_in[0];
    // d_in[1] = seq_lengths: unused by the reference computation
    const float* emb      = (const float*)d_in[2];
    const float* W_ih     = (const float*)d_in[3];
    const float* W_hh     = (const float*)d_in[4];
    const float* b_ih     = (const float*)d_in[5];
    const float* b_hh     = (const float*)d_in[6];
    const float* bn_gamma = (const float*)d_in[7];
    const float* bn_beta  = (const float*)d_in[8];
    const float* bn_mean  = (const float*)d_in[9];
    const float* bn_var   = (const float*)d_in[10];
    const float* fc_w     = (const float*)d_in[11];
    const float* fc_b     = (const float*)d_in[12];

    float* proj = (float*)d_ws;  // VOCAB * 256 * 4 B = 51.2 MB

    wcvt_kernel<<<G4 * EMBED / (256 * 4), 256, 0, stream>>>(W_ih);
    proj_mfma<<<(VOCAB + 63) / 64, 256, 0, stream>>>(emb, b_ih, b_hh, proj);

    lstm_scan<<<BATCH, 64, 0, stream>>>(x, proj, W_hh,
                                        bn_gamma, bn_beta, bn_mean, bn_var,
                                        fc_w, fc_b, (float*)d_out);
}